// Round 1
// baseline (925.528 us; speedup 1.0000x reference)
//
#include <hip/hip_runtime.h>
#include <cstdint>
#include <cstddef>

// Problem constants
#define LQ 1024
#define LK 4096
#define NBATCH 8
#define DM 256
#define NH 4

typedef __attribute__((ext_vector_type(8))) __bf16 bf16x8;
typedef __attribute__((ext_vector_type(4))) float f32x4;
typedef __attribute__((ext_vector_type(4))) unsigned int u32x4;
typedef __attribute__((ext_vector_type(4))) short s16x4;

__device__ __forceinline__ unsigned short f2bf(float f) {
  unsigned int u = __builtin_bit_cast(unsigned int, f);
  u += 0x7FFFu + ((u >> 16) & 1u);          // round-to-nearest-even
  return (unsigned short)(u >> 16);
}

__device__ __forceinline__ bf16x8 ld_bf8(const unsigned short* p) {
  u32x4 u = *reinterpret_cast<const u32x4*>(p);
  return __builtin_bit_cast(bf16x8, u);
}

__device__ __forceinline__ f32x4 zero4() {
  f32x4 v; v.x = 0.f; v.y = 0.f; v.z = 0.f; v.w = 0.f; return v;
}

// ---------------------------------------------------------------------------
// prep: out[(b*L + l)*256 + d] = bf16(a[(l*8+b)*256+d] (+ badd[...]))
// ---------------------------------------------------------------------------
__global__ void prep_add_kernel(const float* __restrict__ a,
                                const float* __restrict__ badd,
                                unsigned short* __restrict__ out,
                                int L, int n) {
  int i = blockIdx.x * blockDim.x + threadIdx.x;
  if (i >= n) return;
  int d = i & 255;
  int rest = i >> 8;
  int bb = rest & 7;
  int l = rest >> 3;
  float v = a[i];
  if (badd) v += badd[i];
  out[(((size_t)bb * L + l) << 8) + d] = f2bf(v);
}

__global__ void conv_bf16_kernel(const float* __restrict__ src,
                                 unsigned short* __restrict__ dst, int n) {
  int i = blockIdx.x * blockDim.x + threadIdx.x;
  if (i < n) dst[i] = f2bf(src[i]);
}

// ---------------------------------------------------------------------------
// Generic NT GEMM: C[m,n] = alpha * sum_k A[m,k]*B[n,k], bf16 in, fp32 acc.
// OUT_MODE 0: fp32 C row-major (ldc). OUT_MODE 1: bf16 C row-major (ldc).
// OUT_MODE 2: bf16 transposed w/ batch fold: out[((m>>12)*1024 + n)*4096 + (m&4095)]
// Tile 128x128xBK64, 256 threads (4 waves, each 64x64 = 4x4 MFMA tiles).
// ---------------------------------------------------------------------------
template <int OUT_MODE>
__global__ void __launch_bounds__(256)
gemm_nt_kernel(const unsigned short* __restrict__ A, int lda, long long sA,
               const unsigned short* __restrict__ B, int ldb, long long sB,
               void* __restrict__ Cv, int ldc, long long sC,
               int K, float alpha) {
  __shared__ __align__(16) unsigned short As[128][72];
  __shared__ __align__(16) unsigned short Bs[128][72];
  const int t = threadIdx.x;
  const int bm0 = blockIdx.y * 128;
  const int bn0 = blockIdx.x * 128;
  A += (size_t)blockIdx.z * sA;
  B += (size_t)blockIdx.z * sB;
  const int lane = t & 63, w = t >> 6;
  const int wm = (w >> 1) * 64, wn = (w & 1) * 64;
  const int lr = lane & 15, quad = lane >> 4;

  f32x4 acc[4][4];
#pragma unroll
  for (int i = 0; i < 4; ++i)
#pragma unroll
    for (int j = 0; j < 4; ++j) acc[i][j] = zero4();

  for (int k0 = 0; k0 < K; k0 += 64) {
#pragma unroll
    for (int c = 0; c < 4; ++c) {
      int ch = t + c * 256;          // 0..1023 chunks of 8 elems
      int r = ch >> 3, col = (ch & 7) << 3;
      *reinterpret_cast<u32x4*>(&As[r][col]) =
          *reinterpret_cast<const u32x4*>(&A[(size_t)(bm0 + r) * lda + k0 + col]);
      *reinterpret_cast<u32x4*>(&Bs[r][col]) =
          *reinterpret_cast<const u32x4*>(&B[(size_t)(bn0 + r) * ldb + k0 + col]);
    }
    __syncthreads();
#pragma unroll
    for (int ks = 0; ks < 2; ++ks) {
      bf16x8 af[4], bfv[4];
#pragma unroll
      for (int i = 0; i < 4; ++i)
        af[i] = ld_bf8(&As[wm + i * 16 + lr][ks * 32 + quad * 8]);
#pragma unroll
      for (int j = 0; j < 4; ++j)
        bfv[j] = ld_bf8(&Bs[wn + j * 16 + lr][ks * 32 + quad * 8]);
#pragma unroll
      for (int i = 0; i < 4; ++i)
#pragma unroll
        for (int j = 0; j < 4; ++j)
          acc[i][j] = __builtin_amdgcn_mfma_f32_16x16x32_bf16(af[i], bfv[j], acc[i][j], 0, 0, 0);
    }
    __syncthreads();
  }

  // Epilogue. C/D layout: col = lane&15, row = quad*4 + reg  (m89-verified)
  if (OUT_MODE == 0) {
    float* C = (float*)Cv + (size_t)blockIdx.z * sC;
#pragma unroll
    for (int i = 0; i < 4; ++i) {
      int m0 = bm0 + wm + i * 16 + quad * 4;
#pragma unroll
      for (int j = 0; j < 4; ++j) {
        int n = bn0 + wn + j * 16 + lr;
#pragma unroll
        for (int r = 0; r < 4; ++r)
          C[(size_t)(m0 + r) * ldc + n] = acc[i][j][r] * alpha;
      }
    }
  } else if (OUT_MODE == 1) {
    unsigned short* C = (unsigned short*)Cv + (size_t)blockIdx.z * sC;
#pragma unroll
    for (int i = 0; i < 4; ++i) {
      int m0 = bm0 + wm + i * 16 + quad * 4;
#pragma unroll
      for (int j = 0; j < 4; ++j) {
        int n = bn0 + wn + j * 16 + lr;
#pragma unroll
        for (int r = 0; r < 4; ++r)
          C[(size_t)(m0 + r) * ldc + n] = f2bf(acc[i][j][r] * alpha);
      }
    }
  } else {
    // transposed bf16 with batch fold (m = b*4096 + kpos -> row b*1024+n, col kpos)
    unsigned short* C = (unsigned short*)Cv;
#pragma unroll
    for (int i = 0; i < 4; ++i) {
      int m0 = bm0 + wm + i * 16 + quad * 4;
      int bb = m0 >> 12;
      int kp = m0 & 4095;
#pragma unroll
      for (int j = 0; j < 4; ++j) {
        int n = bn0 + wn + j * 16 + lr;
        s16x4 pk;
#pragma unroll
        for (int r = 0; r < 4; ++r)
          pk[r] = (short)f2bf(acc[i][j][r] * alpha);
        *reinterpret_cast<s16x4*>(&C[((size_t)(bb * 1024 + n)) * 4096 + kp]) = pk;
      }
    }
  }
}

// ---------------------------------------------------------------------------
// Flash attention: grid (Lq/128, H, B), 512 threads = 8 waves; wave w owns
// q-rows qt*128 + w*16 .. +15. Q pre-scaled by 1/16. K tiles of 32 staged in
// LDS; VT (transposed V) tiles staged in LDS. Online softmax per q-row.
// ---------------------------------------------------------------------------
__global__ void __launch_bounds__(512)
attn_kernel(const unsigned short* __restrict__ Q,
            const unsigned short* __restrict__ Kg,
            const unsigned short* __restrict__ VT,
            unsigned short* __restrict__ O) {
  __shared__ __align__(16) unsigned short Kt[32][264];   // 32 kpos x 256 feat (+8 pad)
  __shared__ __align__(16) unsigned short Vt[256][40];   // 256 e x 32 k (+8 pad)
  __shared__ __align__(16) unsigned short Pl[8][16][40]; // per-wave P 16x32 (+8 pad)
  const int t = threadIdx.x;
  const int qt = blockIdx.x, h = blockIdx.y, b = blockIdx.z;
  const int lane = t & 63, w = t >> 6, lr = lane & 15, quad = lane >> 4;

  const int qrow = qt * 128 + w * 16 + lr;
  const unsigned short* Qb = Q + ((size_t)(b * 1024 + qrow)) * 1024 + h * 256;
  bf16x8 qf[8];
#pragma unroll
  for (int s = 0; s < 8; ++s) qf[s] = ld_bf8(&Qb[s * 32 + quad * 8]);

  f32x4 oacc[16];
#pragma unroll
  for (int j = 0; j < 16; ++j) oacc[j] = zero4();
  float m_r[4], l_r[4], al[4];
#pragma unroll
  for (int r = 0; r < 4; ++r) { m_r[r] = -1e30f; l_r[r] = 0.f; }

  const unsigned short* Kb = Kg + ((size_t)b * 4096) * 1024 + h * 256;
  const unsigned short* Vb = VT + ((size_t)(b * 1024 + h * 256)) * 4096;

  for (int k0 = 0; k0 < 4096; k0 += 32) {
    // stage K tile (32x256) and VT tile (256x32): 1024 chunks of 8 each
#pragma unroll
    for (int c = 0; c < 2; ++c) {
      int ch = t + c * 512;
      {
        int r = ch >> 5, col = (ch & 31) << 3;
        *reinterpret_cast<u32x4*>(&Kt[r][col]) =
            *reinterpret_cast<const u32x4*>(&Kb[(size_t)(k0 + r) * 1024 + col]);
      }
      {
        int r = ch >> 2, col = (ch & 3) << 3;
        *reinterpret_cast<u32x4*>(&Vt[r][col]) =
            *reinterpret_cast<const u32x4*>(&Vb[(size_t)r * 4096 + k0 + col]);
      }
    }
    __syncthreads();

    // S = Q K^T : wave computes 16 q-rows x 32 kpos (two 16x16 C-tiles)
    f32x4 s0 = zero4(), s1 = zero4();
#pragma unroll
    for (int s = 0; s < 8; ++s) {
      bf16x8 b0 = ld_bf8(&Kt[lr][s * 32 + quad * 8]);
      bf16x8 b1 = ld_bf8(&Kt[16 + lr][s * 32 + quad * 8]);
      s0 = __builtin_amdgcn_mfma_f32_16x16x32_bf16(qf[s], b0, s0, 0, 0, 0);
      s1 = __builtin_amdgcn_mfma_f32_16x16x32_bf16(qf[s], b1, s1, 0, 0, 0);
    }

    // online softmax; row = quad*4 + r spread across the quad's 16 lanes
#pragma unroll
    for (int r = 0; r < 4; ++r) {
      float v = fmaxf(s0[r], s1[r]);
      v = fmaxf(v, __shfl_xor(v, 1, 64));
      v = fmaxf(v, __shfl_xor(v, 2, 64));
      v = fmaxf(v, __shfl_xor(v, 4, 64));
      v = fmaxf(v, __shfl_xor(v, 8, 64));
      float mn = fmaxf(m_r[r], v);
      float a = __expf(m_r[r] - mn);
      float p0 = __expf(s0[r] - mn);
      float p1 = __expf(s1[r] - mn);
      float sm = p0 + p1;
      sm += __shfl_xor(sm, 1, 64);
      sm += __shfl_xor(sm, 2, 64);
      sm += __shfl_xor(sm, 4, 64);
      sm += __shfl_xor(sm, 8, 64);
      l_r[r] = l_r[r] * a + sm;
      m_r[r] = mn;
      al[r] = a;
      Pl[w][quad * 4 + r][lr] = f2bf(p0);
      Pl[w][quad * 4 + r][16 + lr] = f2bf(p1);
    }
#pragma unroll
    for (int j = 0; j < 16; ++j) {
#pragma unroll
      for (int r = 0; r < 4; ++r) oacc[j][r] *= al[r];
    }
    // P (A-layout) from per-wave LDS; V from VT tile (B-layout, k-contiguous)
    bf16x8 pa = ld_bf8(&Pl[w][lr][quad * 8]);
#pragma unroll
    for (int j = 0; j < 16; ++j) {
      bf16x8 vb = ld_bf8(&Vt[j * 16 + lr][quad * 8]);
      oacc[j] = __builtin_amdgcn_mfma_f32_16x16x32_bf16(pa, vb, oacc[j], 0, 0, 0);
    }
    __syncthreads();
  }

#pragma unroll
  for (int r = 0; r < 4; ++r) l_r[r] = 1.f / l_r[r];
  const int orow0 = b * 1024 + qt * 128 + w * 16 + quad * 4;
#pragma unroll
  for (int j = 0; j < 16; ++j) {
    int col = h * 256 + j * 16 + lr;
#pragma unroll
    for (int r = 0; r < 4; ++r)
      O[(size_t)(orow0 + r) * 1024 + col] = f2bf(oacc[j][r] * l_r[r]);
  }
}

// ---------------------------------------------------------------------------
// residual + LayerNorm: one wave per row of 256
// ---------------------------------------------------------------------------
__global__ void __launch_bounds__(256)
fc_ln_kernel(const float* __restrict__ fc, const float* __restrict__ tgt,
             const float* __restrict__ g, const float* __restrict__ bb,
             float* __restrict__ y) {
  int row = blockIdx.x * 4 + (threadIdx.x >> 6);  // row = b*1024 + q
  int lane = threadIdx.x & 63;
  int b = row >> 10, q = row & 1023;
  const float* fr = fc + (size_t)row * 256;
  const float* tr = tgt + ((size_t)(q * 8 + b)) * 256;
  float x[4];
  float s = 0.f, ss = 0.f;
#pragma unroll
  for (int e = 0; e < 4; ++e) {
    x[e] = fr[lane + e * 64] + tr[lane + e * 64];
    s += x[e];
    ss += x[e] * x[e];
  }
#pragma unroll
  for (int d = 1; d < 64; d <<= 1) {
    s += __shfl_xor(s, d, 64);
    ss += __shfl_xor(ss, d, 64);
  }
  float mu = s * (1.f / 256.f);
  float var = ss * (1.f / 256.f) - mu * mu;
  float rs = rsqrtf(var + 1e-5f);
  float* yr = y + ((size_t)(q * 8 + b)) * 256;
#pragma unroll
  for (int e = 0; e < 4; ++e)
    yr[lane + e * 64] = (x[e] - mu) * rs * g[lane + e * 64] + bb[lane + e * 64];
}

// ---------------------------------------------------------------------------
extern "C" void kernel_launch(void* const* d_in, const int* in_sizes, int n_in,
                              void* d_out, int out_size, void* d_ws, size_t ws_size,
                              hipStream_t stream) {
  (void)in_sizes; (void)n_in; (void)out_size; (void)ws_size;
  const float* tgt    = (const float*)d_in[0];
  const float* memory = (const float*)d_in[1];
  const float* pos    = (const float*)d_in[2];
  const float* qpos   = (const float*)d_in[3];
  const float* Wq     = (const float*)d_in[4];
  const float* Wk     = (const float*)d_in[5];
  const float* Wv     = (const float*)d_in[6];
  const float* Wfc    = (const float*)d_in[7];
  const float* lng    = (const float*)d_in[8];
  const float* lnb    = (const float*)d_in[9];
  float* out = (float*)d_out;

  char* ws = (char*)d_ws;
  const size_t MB = 1024 * 1024;
  unsigned short* Wq_b  = (unsigned short*)(ws + 0);
  unsigned short* Wk_b  = (unsigned short*)(ws + 512 * 1024);
  unsigned short* Wv_b  = (unsigned short*)(ws + 1 * MB);
  unsigned short* Wfc_b = (unsigned short*)(ws + 1 * MB + 512 * 1024);
  unsigned short* A_q   = (unsigned short*)(ws + 2 * MB);    // [8192,256]   4MB
  unsigned short* A_k   = (unsigned short*)(ws + 6 * MB);    // [32768,256] 16MB
  unsigned short* A_v   = (unsigned short*)(ws + 22 * MB);   // [32768,256] 16MB
  unsigned short* Qall  = (unsigned short*)(ws + 38 * MB);   // [8192,1024] 16MB (pre-scaled 1/16)
  unsigned short* Kall  = (unsigned short*)(ws + 54 * MB);   // [32768,1024] 64MB
  unsigned short* VTb   = (unsigned short*)(ws + 118 * MB);  // [8192,4096] 64MB (transposed V)
  unsigned short* Oall  = (unsigned short*)(ws + 2 * MB);    // aliases A_q/A_k (dead) 16MB
  float* fcout          = (float*)(ws + 18 * MB);            // aliases A_k/A_v (dead)  8MB
  float* y = out;
  float* attn_mean = out + (size_t)LQ * NBATCH * DM;         // + 2,097,152

  int n_q = LQ * NBATCH * DM;   // 2,097,152
  int n_k = LK * NBATCH * DM;   // 8,388,608
  prep_add_kernel<<<(n_q + 255) / 256, 256, 0, stream>>>(tgt, qpos, A_q, LQ, n_q);
  prep_add_kernel<<<(n_k + 255) / 256, 256, 0, stream>>>(memory, pos, A_k, LK, n_k);
  prep_add_kernel<<<(n_k + 255) / 256, 256, 0, stream>>>(memory, nullptr, A_v, LK, n_k);
  int n_w = 1024 * 256;
  conv_bf16_kernel<<<(n_w + 255) / 256, 256, 0, stream>>>(Wq, Wq_b, n_w);
  conv_bf16_kernel<<<(n_w + 255) / 256, 256, 0, stream>>>(Wk, Wk_b, n_w);
  conv_bf16_kernel<<<(n_w + 255) / 256, 256, 0, stream>>>(Wv, Wv_b, n_w);
  conv_bf16_kernel<<<(n_w + 255) / 256, 256, 0, stream>>>(Wfc, Wfc_b, n_w);

  // Q projection (scale 1/16 folded in), bf16 out
  gemm_nt_kernel<1><<<dim3(8, 64, 1), 256, 0, stream>>>(
      A_q, 256, 0LL, Wq_b, 256, 0LL, (void*)Qall, 1024, 0LL, 256, 0.0625f);
  // K projection
  gemm_nt_kernel<1><<<dim3(8, 256, 1), 256, 0, stream>>>(
      A_k, 256, 0LL, Wk_b, 256, 0LL, (void*)Kall, 1024, 0LL, 256, 1.0f);
  // V projection, written transposed: VT[(b*1024+e)*4096 + k]
  gemm_nt_kernel<2><<<dim3(8, 256, 1), 256, 0, stream>>>(
      A_v, 256, 0LL, Wv_b, 256, 0LL, (void*)VTb, 0, 0LL, 256, 1.0f);
  // attn_mean = 0.25 * Qall_b . Kall_b^T  (concat-dot == sum over heads), fp32 to d_out
  gemm_nt_kernel<0><<<dim3(32, 8, 8), 256, 0, stream>>>(
      Qall, 1024, (long long)(1024 * 1024), Kall, 1024, (long long)(4096 * 1024),
      (void*)attn_mean, 4096, (long long)4096 * 1024, 1024, 0.25f);
  // flash attention
  attn_kernel<<<dim3(8, NH, NBATCH), 512, 0, stream>>>(Qall, Kall, VTb, Oall);
  // fc: [8192,1024] @ Wfc[256,1024]^T -> fp32 [8192,256]
  gemm_nt_kernel<0><<<dim3(2, 64, 1), 256, 0, stream>>>(
      Oall, 1024, 0LL, Wfc_b, 1024, 0LL, (void*)fcout, 256, 0LL, 1024, 1.0f);
  // residual + LN
  fc_ln_kernel<<<2048, 256, 0, stream>>>(fcout, tgt, lng, lnb, y);
}